// Round 5
// baseline (1260.799 us; speedup 1.0000x reference)
//
#include <hip/hip_runtime.h>
#include <stdint.h>

#define DIMM 1024
#define NSEQ 1024
#define BB 2
#define HEADSN 16
#define MLPD 4096
#define DEPTHN 4
#define MROWS (BB*NSEQ)  // 2048
#define VSTR 10240       // canonical per-layer vec stride (elements)

typedef __bf16 bf16x8 __attribute__((ext_vector_type(8)));
typedef float f32x4 __attribute__((ext_vector_type(4)));

__device__ __forceinline__ float bf2f(unsigned short u) {
    union { uint32_t i; float f; } x; x.i = ((uint32_t)u) << 16; return x.f;
}
__device__ __forceinline__ unsigned short f2bf(float f) {
    union { uint32_t i; float f; } x; x.f = f;
    uint32_t r = x.i + 0x7fffu + ((x.i >> 16) & 1u);
    return (unsigned short)(r >> 16);
}
__device__ __forceinline__ float loadf(const void* p, size_t i, int f32) {
    return f32 ? ((const float*)p)[i] : bf2f(((const unsigned short*)p)[i]);
}

// async global->LDS, 16B per lane; LDS dest = wave-uniform base + lane*16
__device__ __forceinline__ void gl_lds16(const unsigned short* g, unsigned short* l) {
    __builtin_amdgcn_global_load_lds(
        (const __attribute__((address_space(1))) uint32_t*)g,
        (__attribute__((address_space(3))) uint32_t*)l,
        16, 0, 0);
}

// ---------------- dtype sniff ----------------
__global__ __launch_bounds__(256) void sniff_kernel(const unsigned short* __restrict__ x,
                                                    int* __restrict__ flag) {
    __shared__ int cnt[256];
    int tid = threadIdx.x;
    int c = 0;
    for (int i = tid * 2; i < 65536; i += 512) {
        int e = (x[i] >> 7) & 0xFF;
        if (e >= 0x8A) c++;
    }
    cnt[tid] = c;
    __syncthreads();
    for (int s = 128; s > 0; s >>= 1) {
        if (tid < s) cnt[tid] += cnt[tid + s];
        __syncthreads();
    }
    if (tid == 0) flag[0] = (cnt[0] > 32) ? 1 : 0;
}

// ---------------- converts ----------------
__global__ __launch_bounds__(256) void cvt_x(const void* __restrict__ x, float* __restrict__ xf,
                                             const int* __restrict__ flag) {
    int f = flag[0];
    int i = blockIdx.x * 256 + threadIdx.x;
    xf[i] = loadf(x, i, f);
}
__global__ __launch_bounds__(256) void store_out(const float* __restrict__ xf, void* __restrict__ out,
                                                 const int* __restrict__ flag) {
    int f = flag[0];
    int i = blockIdx.x * 256 + threadIdx.x;
    float v = xf[i];
    if (f) ((float*)out)[i] = v;
    else   ((unsigned short*)out)[i] = f2bf(v);
}
// all 7 small vectors in one launch; grid (64, 7)
__global__ __launch_bounds__(256) void conv_all(const void* s0, const void* s1, const void* s2,
                                                const void* s3, const void* s4, const void* s5,
                                                const void* s6, unsigned short* __restrict__ dst,
                                                const int* __restrict__ flag) {
    int f = flag[0];
    const void* src; int len, off;
    switch (blockIdx.y) {
        case 0: src = s0; len = 1024; off = 0;    break;
        case 1: src = s1; len = 1024; off = 1024; break;
        case 2: src = s2; len = 1024; off = 2048; break;
        case 3: src = s3; len = 1024; off = 3072; break;
        case 4: src = s4; len = 1024; off = 4096; break;
        case 5: src = s5; len = 1024; off = 5120; break;
        default: src = s6; len = 4096; off = 6144; break;
    }
    int i = blockIdx.x * 256 + threadIdx.x;
    if (i < DEPTHN * len) {
        int l = i / len, o = i - l * len;
        dst[l * VSTR + off + o] = f2bf(loadf(src, i, f));
    }
}

// ---------------- transpose+convert: src[srcOffE + k*N + n] -> bf16 out[n*K + k] ----------------
__global__ __launch_bounds__(256) void transpose_conv(const void* __restrict__ in, size_t srcOffE,
                                                      unsigned short* __restrict__ out,
                                                      int K, int N, const int* __restrict__ flag) {
    int f = flag[0];
    __shared__ unsigned short t[32][33];
    int n0 = blockIdx.x * 32, k0 = blockIdx.y * 32;
    int tx = threadIdx.x, ty = threadIdx.y;  // 32 x 8
#pragma unroll
    for (int i = 0; i < 4; i++) {
        int k = k0 + ty + i * 8;
        t[ty + i * 8][tx] = f2bf(loadf(in, srcOffE + (size_t)k * N + n0 + tx, f));
    }
    __syncthreads();
#pragma unroll
    for (int i = 0; i < 4; i++) {
        int n = n0 + ty + i * 8;
        out[(size_t)n * K + k0 + tx] = t[tx][ty + i * 8];
    }
}

// ---------------- V^T per layer ----------------
__global__ __launch_bounds__(256) void vt_kernel(const unsigned short* __restrict__ qkv,
                                                 unsigned short* __restrict__ vt) {
    __shared__ unsigned short t[32][33];
    int b = blockIdx.z;
    int c0 = blockIdx.x * 32, k0 = blockIdx.y * 32;
    int tx = threadIdx.x, ty = threadIdx.y;  // 32 x 8
#pragma unroll
    for (int i = 0; i < 4; i++) {
        int k = k0 + ty + i * 8;
        t[ty + i * 8][tx] = qkv[(size_t)(b * 1024 + k) * 3072 + 2048 + c0 + tx];
    }
    __syncthreads();
#pragma unroll
    for (int i = 0; i < 4; i++) {
        int c = c0 + ty + i * 8;
        vt[(size_t)(b * 1024 + c) * 1024 + k0 + tx] = t[tx][ty + i * 8];
    }
}

// ---------------- mask -> bitmask u64 words ----------------
__global__ __launch_bounds__(256) void mask_pack(const int* __restrict__ mask,
                                                 unsigned long long* __restrict__ bits) {
    int wid = (blockIdx.x * 256 + threadIdx.x) >> 6;
    int lane = threadIdx.x & 63;
#pragma unroll
    for (int i = 0; i < 16; i++) {
        int w = wid * 16 + i;
        int mv = mask[(size_t)w * 64 + lane];
        unsigned long long bl = __ballot(mv != 0);
        if (lane == 0) bits[w] = bl;
    }
}

// ---------------- LayerNorm ----------------
__global__ __launch_bounds__(256) void ln_kernel(const float* __restrict__ x,
                                                 const unsigned short* __restrict__ g,
                                                 const unsigned short* __restrict__ bta,
                                                 unsigned short* __restrict__ out) {
    int row = blockIdx.x, tid = threadIdx.x;
    const float* xr = x + (size_t)row * DIMM;
    float v[4]; float s = 0.f, s2 = 0.f;
#pragma unroll
    for (int i = 0; i < 4; i++) { v[i] = xr[tid + i * 256]; s += v[i]; s2 += v[i] * v[i]; }
#pragma unroll
    for (int off = 32; off >= 1; off >>= 1) {
        s  += __shfl_down(s, off, 64);
        s2 += __shfl_down(s2, off, 64);
    }
    __shared__ float rs[4], rs2[4];
    int wv = tid >> 6;
    if ((tid & 63) == 0) { rs[wv] = s; rs2[wv] = s2; }
    __syncthreads();
    s  = rs[0] + rs[1] + rs[2] + rs[3];
    s2 = rs2[0] + rs2[1] + rs2[2] + rs2[3];
    float mu  = s * (1.f / DIMM);
    float var = s2 * (1.f / DIMM) - mu * mu;
    float rr  = rsqrtf(var + 1e-5f);
#pragma unroll
    for (int i = 0; i < 4; i++) {
        int c = tid + i * 256;
        float y = (v[i] - mu) * rr * bf2f(g[c]) + bf2f(bta[c]);
        out[(size_t)row * DIMM + c] = f2bf(y);
    }
}

// ---------------- GEMM, double-buffered async pipeline ----------------
// A[M,K] x Bt[N,K]; 128x128 tile, BK=32, LDS 2x(8KB+8KB)=32KB.
// Loads for tile k+1 are issued right after the barrier, before computing tile k,
// so the vmcnt drain at the next barrier overlaps a full compute phase.
// MODE 0: store bf16 C   MODE 1: Cres(fp32) += acc(+bias)   MODE 2: bf16 gelu(acc+bias)
template <int MODE, int SPLITK>
__global__ __launch_bounds__(256) void gemm_bt(const unsigned short* __restrict__ A,
                                               const unsigned short* __restrict__ Bt,
                                               const unsigned short* __restrict__ bias,
                                               unsigned short* __restrict__ Cbf,
                                               float* __restrict__ Cres,
                                               int M, int N, int K) {
    __shared__ __align__(16) unsigned short As[2][128 * 32];
    __shared__ __align__(16) unsigned short Bs[2][128 * 32];
    const int tid = threadIdx.x;
    const int mBase = blockIdx.y * 128, nBase = blockIdx.x * 128;
    const int w = tid >> 6, lane = tid & 63;
    const int wm = (w >> 1) * 64, wn = (w & 1) * 64;
    const int quad = lane >> 4, l16 = lane & 15;
    const int kLen = K / SPLITK;
    const int kStart = (SPLITK > 1) ? blockIdx.z * kLen : 0;

    f32x4 acc[4][4];
#pragma unroll
    for (int i = 0; i < 4; i++)
#pragma unroll
        for (int j = 0; j < 4; j++) acc[i][j] = (f32x4){0.f, 0.f, 0.f, 0.f};

    // staging: wave w stages rows [w*32, w*32+32) as 2 chunks of 16 rows; 16B/lane.
    const int lr = lane >> 2, lc = (lane & 3) * 8;
    const unsigned short* Ag = A  + (size_t)(mBase + w * 32 + lr) * K + kStart + lc;
    const unsigned short* Bg = Bt + (size_t)(nBase + w * 32 + lr) * K + kStart + lc;
    const size_t rstep = (size_t)16 * K;

#define STAGE(buf, kk)                                             \
    do {                                                           \
        gl_lds16(Ag + (kk),         &As[buf][(w * 32) * 32]);      \
        gl_lds16(Ag + (kk) + rstep, &As[buf][(w * 32 + 16) * 32]); \
        gl_lds16(Bg + (kk),         &Bs[buf][(w * 32) * 32]);      \
        gl_lds16(Bg + (kk) + rstep, &Bs[buf][(w * 32 + 16) * 32]); \
    } while (0)

#define COMPUTE(buf)                                                                    \
    do {                                                                                \
        bf16x8 af[4], bfv[4];                                                           \
        _Pragma("unroll")                                                               \
        for (int i = 0; i < 4; i++)                                                     \
            af[i] = *(const bf16x8*)&As[buf][(wm + i * 16 + l16) * 32 + quad * 8];      \
        _Pragma("unroll")                                                               \
        for (int j = 0; j < 4; j++)                                                     \
            bfv[j] = *(const bf16x8*)&Bs[buf][(wn + j * 16 + l16) * 32 + quad * 8];     \
        _Pragma("unroll")                                                               \
        for (int i = 0; i < 4; i++)                                                     \
            _Pragma("unroll")                                                           \
            for (int j = 0; j < 4; j++)                                                 \
                acc[i][j] = __builtin_amdgcn_mfma_f32_16x16x32_bf16(af[i], bfv[j],      \
                                                                    acc[i][j], 0, 0, 0);\
    } while (0)

    STAGE(0, 0);
    for (int k0 = 0; k0 < kLen; k0 += 64) {
        __syncthreads();                       // drains loads into buf0 (issued 1 phase ago)
        if (k0 + 32 < kLen) STAGE(1, k0 + 32); // overlap with compute(buf0)
        COMPUTE(0);
        __syncthreads();                       // drains loads into buf1
        if (k0 + 64 < kLen) STAGE(0, k0 + 64); // overlap with compute(buf1)
        COMPUTE(1);
    }
#undef STAGE
#undef COMPUTE

#pragma unroll
    for (int i = 0; i < 4; i++) {
#pragma unroll
        for (int j = 0; j < 4; j++) {
#pragma unroll
            for (int r = 0; r < 4; r++) {
                int m = mBase + wm + i * 16 + quad * 4 + r;
                int n = nBase + wn + j * 16 + l16;
                float v = acc[i][j][r];
                size_t idx = (size_t)m * N + n;
                if (MODE == 0) {
                    Cbf[idx] = f2bf(v);
                } else if (MODE == 1) {
                    if (SPLITK > 1) {
                        if (blockIdx.z == 0) v += bf2f(bias[n]);
                        atomicAdd(&Cres[idx], v);
                    } else {
                        Cres[idx] += v + bf2f(bias[n]);
                    }
                } else {
                    float t2 = v + bf2f(bias[n]);
                    float gg = 0.5f * t2 * (1.f + erff(t2 * 0.70710678118f));
                    Cbf[idx] = f2bf(gg);
                }
            }
        }
    }
}

// ---------------- MFMA flash attention ----------------
__global__ __launch_bounds__(256) void attn_mfma(const unsigned short* __restrict__ qkv,
                                                 const unsigned short* __restrict__ vt,
                                                 const unsigned long long* __restrict__ mbits,
                                                 unsigned short* __restrict__ o) {
    __shared__ __align__(16) unsigned short Ks[64 * 72];
    __shared__ __align__(16) unsigned short Vs[64 * 72];
    __shared__ __align__(16) unsigned short Ps[4][16 * 68];

    const int tid = threadIdx.x, w = tid >> 6, lane = tid & 63;
    const int quad = lane >> 4, l16 = lane & 15;
    const int qt = blockIdx.x, h = blockIdx.y, b = blockIdx.z;

    const size_t qrow = (size_t)(b * NSEQ + qt * 64 + w * 16 + l16) * 3072 + h * 64;
    bf16x8 qf[2];
    qf[0] = *(const bf16x8*)(qkv + qrow + quad * 8);
    qf[1] = *(const bf16x8*)(qkv + qrow + 32 + quad * 8);

    const int srow = tid >> 2, scol = (tid & 3) * 16;
    const unsigned short* kg_base = qkv + (size_t)(b * NSEQ) * 3072 + 1024 + h * 64;
    const unsigned short* vg_base = vt + (size_t)((b * HEADSN + h) * 64 + srow) * 1024;

    f32x4 oacc[4];
#pragma unroll
    for (int j = 0; j < 4; j++) oacc[j] = (f32x4){0.f, 0.f, 0.f, 0.f};
    float m_run[4], l_run[4];
#pragma unroll
    for (int r = 0; r < 4; r++) { m_run[r] = -1e30f; l_run[r] = 0.f; }

    const unsigned long long* mb =
        mbits + ((size_t)(b * NSEQ + qt * 64 + w * 16 + quad * 4)) * 16;

    for (int kt = 0; kt < 16; kt++) {
        __syncthreads();
        {
            const unsigned short* kg = kg_base + (size_t)(kt * 64 + srow) * 3072 + scol;
            uint4 k0 = *(const uint4*)kg;
            uint4 k1 = *(const uint4*)(kg + 8);
            const unsigned short* vg = vg_base + kt * 64 + scol;
            uint4 v0 = *(const uint4*)vg;
            uint4 v1 = *(const uint4*)(vg + 8);
            *(uint4*)&Ks[srow * 72 + scol]     = k0;
            *(uint4*)&Ks[srow * 72 + scol + 8] = k1;
            *(uint4*)&Vs[srow * 72 + scol]     = v0;
            *(uint4*)&Vs[srow * 72 + scol + 8] = v1;
        }
        __syncthreads();

        f32x4 sacc[4];
#pragma unroll
        for (int j = 0; j < 4; j++) sacc[j] = (f32x4){0.f, 0.f, 0.f, 0.f};
#pragma unroll
        for (int ks = 0; ks < 2; ks++) {
#pragma unroll
            for (int j = 0; j < 4; j++) {
                bf16x8 kf = *(const bf16x8*)&Ks[(j * 16 + l16) * 72 + ks * 32 + quad * 8];
                sacc[j] = __builtin_amdgcn_mfma_f32_16x16x32_bf16(qf[ks], kf, sacc[j], 0, 0, 0);
            }
        }

        unsigned long long mw[4];
#pragma unroll
        for (int r = 0; r < 4; r++) mw[r] = mb[r * 16 + kt];

        float sv[4][4];
        float tmax[4];
#pragma unroll
        for (int r = 0; r < 4; r++) {
            float mx = -1e30f;
#pragma unroll
            for (int j = 0; j < 4; j++) {
                float t = sacc[j][r] * 0.125f;
                int keep = (int)((mw[r] >> (j * 16 + l16)) & 1ull);
                t = keep ? t : -1e9f;
                sv[j][r] = t;
                mx = fmaxf(mx, t);
            }
#pragma unroll
            for (int off = 1; off < 16; off <<= 1)
                mx = fmaxf(mx, __shfl_xor(mx, off, 64));
            tmax[r] = mx;
        }
#pragma unroll
        for (int r = 0; r < 4; r++) {
            float m_new = fmaxf(m_run[r], tmax[r]);
            float alpha = __expf(m_run[r] - m_new);
            m_run[r] = m_new;
            float pj[4], ps = 0.f;
#pragma unroll
            for (int j = 0; j < 4; j++) {
                pj[j] = __expf(sv[j][r] - m_new);
                ps += pj[j];
            }
#pragma unroll
            for (int off = 1; off < 16; off <<= 1)
                ps += __shfl_xor(ps, off, 64);
            l_run[r] = l_run[r] * alpha + ps;
#pragma unroll
            for (int j = 0; j < 4; j++) {
                oacc[j][r] *= alpha;
                Ps[w][(quad * 4 + r) * 68 + j * 16 + l16] = f2bf(pj[j]);
            }
        }

#pragma unroll
        for (int ks = 0; ks < 2; ks++) {
            const unsigned short* pr = &Ps[w][l16 * 68 + ks * 32 + quad * 8];
            union { ushort4 u[2]; bf16x8 v; } af;
            af.u[0] = *(const ushort4*)pr;
            af.u[1] = *(const ushort4*)(pr + 4);
#pragma unroll
            for (int j = 0; j < 4; j++) {
                bf16x8 vf = *(const bf16x8*)&Vs[(j * 16 + l16) * 72 + ks * 32 + quad * 8];
                oacc[j] = __builtin_amdgcn_mfma_f32_16x16x32_bf16(af.v, vf, oacc[j], 0, 0, 0);
            }
        }
    }

#pragma unroll
    for (int j = 0; j < 4; j++) {
#pragma unroll
        for (int r = 0; r < 4; r++) {
            size_t row = (size_t)(b * NSEQ + qt * 64 + w * 16 + quad * 4 + r);
            o[row * 1024 + h * 64 + j * 16 + l16] = f2bf(oacc[j][r] / l_run[r]);
        }
    }
}

extern "C" void kernel_launch(void* const* d_in, const int* in_sizes, int n_in,
                              void* d_out, int out_size, void* d_ws, size_t ws_size,
                              hipStream_t stream) {
    const void* x     = d_in[0];
    const int*  mask  = (const int*)d_in[1];
    const void* ln1_g = d_in[2];
    const void* ln1_b = d_in[3];
    const void* qkv_w = d_in[4];
    const void* out_w = d_in[5];
    const void* out_b = d_in[6];
    const void* ln2_g = d_in[7];
    const void* ln2_b = d_in[8];
    const void* ff1_w = d_in[9];
    const void* ff1_b = d_in[10];
    const void* ff2_w = d_in[11];
    const void* ff2_b = d_in[12];

    char* ws = (char*)d_ws;
    float*          xf     = (float*)ws;                            // 8 MB fp32 residual
    unsigned short* h_bf   = (unsigned short*)(ws + (8u  << 20));   // 4 MB LN out
    unsigned short* qkv_bf = (unsigned short*)(ws + (12u << 20));   // 12 MB (attn half)
    unsigned short* ff_bf  = (unsigned short*)(ws + (12u << 20));   // 16 MB (ff half, reuses qkv+vt)
    unsigned short* vt_bf  = (unsigned short*)(ws + (24u << 20));   // 4 MB V^T (attn half)
    unsigned short* o_bf   = (unsigned short*)(ws + (28u << 20));   // 4 MB
    unsigned short* wT     = (unsigned short*)(ws + (32u << 20));   // 8 MB transposed weight
    unsigned short* vecs   = (unsigned short*)(ws + (40u << 20));   // 80 KB canonical vecs
    int*            flag   = (int*)(ws + (40u << 20) + (128u << 10));
    unsigned long long* mbits = (unsigned long long*)(ws + (40u << 20) + (192u << 10)); // 256 KB

    sniff_kernel<<<1, 256, 0, stream>>>((const unsigned short*)x, flag);

    conv_all<<<dim3(64, 7), 256, 0, stream>>>(ln1_g, ln1_b, out_b, ln2_g, ln2_b, ff2_b, ff1_b,
                                              vecs, flag);
    mask_pack<<<512, 256, 0, stream>>>(mask, mbits);

    const int nx = MROWS * DIMM;  // 2M
    cvt_x<<<nx / 256, 256, 0, stream>>>(x, xf, flag);

    for (int l = 0; l < DEPTHN; l++) {
        const unsigned short* lv = vecs + l * VSTR;
        // --- attention half ---
        ln_kernel<<<MROWS, 256, 0, stream>>>(xf, lv + 0, lv + 1024, h_bf);
        transpose_conv<<<dim3(3072 / 32, 1024 / 32), dim3(32, 8), 0, stream>>>(
            qkv_w, (size_t)l * 1024 * 3072, wT, 1024, 3072, flag);
        gemm_bt<0, 1><<<dim3(3072 / 128, MROWS / 128), 256, 0, stream>>>(
            h_bf, wT, nullptr, qkv_bf, nullptr, MROWS, 3072, 1024);
        vt_kernel<<<dim3(32, 32, BB), dim3(32, 8), 0, stream>>>(qkv_bf, vt_bf);
        attn_mfma<<<dim3(NSEQ / 64, HEADSN, BB), 256, 0, stream>>>(qkv_bf, vt_bf, mbits, o_bf);
        transpose_conv<<<dim3(1024 / 32, 1024 / 32), dim3(32, 8), 0, stream>>>(
            out_w, (size_t)l * 1024 * 1024, wT, 1024, 1024, flag);
        gemm_bt<1, 4><<<dim3(1024 / 128, MROWS / 128, 4), 256, 0, stream>>>(
            o_bf, wT, lv + 2048, nullptr, xf, MROWS, 1024, 1024);
        // --- feedforward half ---
        ln_kernel<<<MROWS, 256, 0, stream>>>(xf, lv + 3072, lv + 4096, h_bf);
        transpose_conv<<<dim3(4096 / 32, 1024 / 32), dim3(32, 8), 0, stream>>>(
            ff1_w, (size_t)l * 1024 * 4096, wT, 1024, 4096, flag);
        gemm_bt<2, 1><<<dim3(4096 / 128, MROWS / 128), 256, 0, stream>>>(
            h_bf, wT, lv + 6144, ff_bf, nullptr, MROWS, 4096, 1024);
        transpose_conv<<<dim3(1024 / 32, 4096 / 32), dim3(32, 8), 0, stream>>>(
            ff2_w, (size_t)l * 4096 * 1024, wT, 4096, 1024, flag);
        gemm_bt<1, 8><<<dim3(1024 / 128, MROWS / 128, 8), 256, 0, stream>>>(
            ff_bf, wT, lv + 5120, nullptr, xf, MROWS, 1024, 4096);
    }

    store_out<<<nx / 256, 256, 0, stream>>>(xf, d_out, flag);
}

// Round 6
// 1044.362 us; speedup vs baseline: 1.2072x; 1.2072x over previous
//
#include <hip/hip_runtime.h>
#include <stdint.h>

#define DIMM 1024
#define NSEQ 1024
#define BB 2
#define HEADSN 16
#define MLPD 4096
#define DEPTHN 4
#define MROWS (BB*NSEQ)  // 2048
#define VSTR 10240       // canonical per-layer vec stride (elements)

typedef __bf16 bf16x8 __attribute__((ext_vector_type(8)));
typedef float f32x4 __attribute__((ext_vector_type(4)));

__device__ __forceinline__ float bf2f(unsigned short u) {
    union { uint32_t i; float f; } x; x.i = ((uint32_t)u) << 16; return x.f;
}
__device__ __forceinline__ unsigned short f2bf(float f) {
    union { uint32_t i; float f; } x; x.f = f;
    uint32_t r = x.i + 0x7fffu + ((x.i >> 16) & 1u);
    return (unsigned short)(r >> 16);
}
__device__ __forceinline__ float loadf(const void* p, size_t i, int f32) {
    return f32 ? ((const float*)p)[i] : bf2f(((const unsigned short*)p)[i]);
}

// async global->LDS, 16B per lane; LDS dest = wave-uniform base + lane*16
__device__ __forceinline__ void gl_lds16(const unsigned short* g, unsigned short* l) {
    __builtin_amdgcn_global_load_lds(
        (const __attribute__((address_space(1))) uint32_t*)g,
        (__attribute__((address_space(3))) uint32_t*)l,
        16, 0, 0);
}

// ---------------- dtype sniff ----------------
__global__ __launch_bounds__(256) void sniff_kernel(const unsigned short* __restrict__ x,
                                                    int* __restrict__ flag) {
    __shared__ int cnt[256];
    int tid = threadIdx.x;
    int c = 0;
    for (int i = tid * 2; i < 65536; i += 512) {
        int e = (x[i] >> 7) & 0xFF;
        if (e >= 0x8A) c++;
    }
    cnt[tid] = c;
    __syncthreads();
    for (int s = 128; s > 0; s >>= 1) {
        if (tid < s) cnt[tid] += cnt[tid + s];
        __syncthreads();
    }
    if (tid == 0) flag[0] = (cnt[0] > 32) ? 1 : 0;
}

// ---------------- converts ----------------
__global__ __launch_bounds__(256) void cvt_x(const void* __restrict__ x, float* __restrict__ xf,
                                             const int* __restrict__ flag) {
    int f = flag[0];
    int i = blockIdx.x * 256 + threadIdx.x;
    xf[i] = loadf(x, i, f);
}
__global__ __launch_bounds__(256) void store_out(const float* __restrict__ xf, void* __restrict__ out,
                                                 const int* __restrict__ flag) {
    int f = flag[0];
    int i = blockIdx.x * 256 + threadIdx.x;
    float v = xf[i];
    if (f) ((float*)out)[i] = v;
    else   ((unsigned short*)out)[i] = f2bf(v);
}
// all 7 small vectors in one launch; grid (64, 7)
__global__ __launch_bounds__(256) void conv_all(const void* s0, const void* s1, const void* s2,
                                                const void* s3, const void* s4, const void* s5,
                                                const void* s6, unsigned short* __restrict__ dst,
                                                const int* __restrict__ flag) {
    int f = flag[0];
    const void* src; int len, off;
    switch (blockIdx.y) {
        case 0: src = s0; len = 1024; off = 0;    break;
        case 1: src = s1; len = 1024; off = 1024; break;
        case 2: src = s2; len = 1024; off = 2048; break;
        case 3: src = s3; len = 1024; off = 3072; break;
        case 4: src = s4; len = 1024; off = 4096; break;
        case 5: src = s5; len = 1024; off = 5120; break;
        default: src = s6; len = 4096; off = 6144; break;
    }
    int i = blockIdx.x * 256 + threadIdx.x;
    if (i < DEPTHN * len) {
        int l = i / len, o = i - l * len;
        dst[l * VSTR + off + o] = f2bf(loadf(src, i, f));
    }
}

// ---------------- transpose+convert: src[srcOffE + k*N + n] -> bf16 out[n*K + k] ----------------
__global__ __launch_bounds__(256) void transpose_conv(const void* __restrict__ in, size_t srcOffE,
                                                      unsigned short* __restrict__ out,
                                                      int K, int N, const int* __restrict__ flag) {
    int f = flag[0];
    __shared__ unsigned short t[32][33];
    int n0 = blockIdx.x * 32, k0 = blockIdx.y * 32;
    int tx = threadIdx.x, ty = threadIdx.y;  // 32 x 8
#pragma unroll
    for (int i = 0; i < 4; i++) {
        int k = k0 + ty + i * 8;
        t[ty + i * 8][tx] = f2bf(loadf(in, srcOffE + (size_t)k * N + n0 + tx, f));
    }
    __syncthreads();
#pragma unroll
    for (int i = 0; i < 4; i++) {
        int n = n0 + ty + i * 8;
        out[(size_t)n * K + k0 + tx] = t[tx][ty + i * 8];
    }
}

// ---------------- V^T per layer ----------------
__global__ __launch_bounds__(256) void vt_kernel(const unsigned short* __restrict__ qkv,
                                                 unsigned short* __restrict__ vt) {
    __shared__ unsigned short t[32][33];
    int b = blockIdx.z;
    int c0 = blockIdx.x * 32, k0 = blockIdx.y * 32;
    int tx = threadIdx.x, ty = threadIdx.y;  // 32 x 8
#pragma unroll
    for (int i = 0; i < 4; i++) {
        int k = k0 + ty + i * 8;
        t[ty + i * 8][tx] = qkv[(size_t)(b * 1024 + k) * 3072 + 2048 + c0 + tx];
    }
    __syncthreads();
#pragma unroll
    for (int i = 0; i < 4; i++) {
        int c = c0 + ty + i * 8;
        vt[(size_t)(b * 1024 + c) * 1024 + k0 + tx] = t[tx][ty + i * 8];
    }
}

// ---------------- mask -> bitmask u64 words ----------------
__global__ __launch_bounds__(256) void mask_pack(const int* __restrict__ mask,
                                                 unsigned long long* __restrict__ bits) {
    int wid = (blockIdx.x * 256 + threadIdx.x) >> 6;
    int lane = threadIdx.x & 63;
#pragma unroll
    for (int i = 0; i < 16; i++) {
        int w = wid * 16 + i;
        int mv = mask[(size_t)w * 64 + lane];
        unsigned long long bl = __ballot(mv != 0);
        if (lane == 0) bits[w] = bl;
    }
}

// ---------------- LayerNorm (standalone; only for the first pre-attn LN) ----------------
__global__ __launch_bounds__(256) void ln_kernel(const float* __restrict__ x,
                                                 const unsigned short* __restrict__ g,
                                                 const unsigned short* __restrict__ bta,
                                                 unsigned short* __restrict__ out) {
    int row = blockIdx.x, tid = threadIdx.x;
    const float* xr = x + (size_t)row * DIMM;
    float v[4]; float s = 0.f, s2 = 0.f;
#pragma unroll
    for (int i = 0; i < 4; i++) { v[i] = xr[tid + i * 256]; s += v[i]; s2 += v[i] * v[i]; }
#pragma unroll
    for (int off = 32; off >= 1; off >>= 1) {
        s  += __shfl_down(s, off, 64);
        s2 += __shfl_down(s2, off, 64);
    }
    __shared__ float rs[4], rs2[4];
    int wv = tid >> 6;
    if ((tid & 63) == 0) { rs[wv] = s; rs2[wv] = s2; }
    __syncthreads();
    s  = rs[0] + rs[1] + rs[2] + rs[3];
    s2 = rs2[0] + rs2[1] + rs2[2] + rs2[3];
    float mu  = s * (1.f / DIMM);
    float var = s2 * (1.f / DIMM) - mu * mu;
    float rr  = rsqrtf(var + 1e-5f);
#pragma unroll
    for (int i = 0; i < 4; i++) {
        int c = tid + i * 256;
        float y = (v[i] - mu) * rr * bf2f(g[c]) + bf2f(bta[c]);
        out[(size_t)row * DIMM + c] = f2bf(y);
    }
}

// ---------------- split-K slab reduce + residual update (+ optional fused LN) ----------------
// xf[row] += bias + sum_z slab[z][row]; optionally LayerNorm(result) -> out (bf16).
template <int S, int HAS_LN>
__global__ __launch_bounds__(256) void reduce_ln(const float* __restrict__ slab,
                                                 const unsigned short* __restrict__ bias,
                                                 float* __restrict__ xf,
                                                 const unsigned short* __restrict__ g,
                                                 const unsigned short* __restrict__ bta,
                                                 unsigned short* __restrict__ out) {
    const size_t SL = (size_t)MROWS * DIMM;
    int row = blockIdx.x, tid = threadIdx.x;
    float v[4]; float s = 0.f, s2 = 0.f;
#pragma unroll
    for (int i = 0; i < 4; i++) {
        int c = tid + i * 256;
        size_t idx = (size_t)row * DIMM + c;
        float t = xf[idx] + bf2f(bias[c]);
#pragma unroll
        for (int z = 0; z < S; z++) t += slab[z * SL + idx];
        xf[idx] = t;
        v[i] = t; s += t; s2 += t * t;
    }
    if (HAS_LN) {
#pragma unroll
        for (int off = 32; off >= 1; off >>= 1) {
            s  += __shfl_down(s, off, 64);
            s2 += __shfl_down(s2, off, 64);
        }
        __shared__ float rs[4], rs2[4];
        int wv = tid >> 6;
        if ((tid & 63) == 0) { rs[wv] = s; rs2[wv] = s2; }
        __syncthreads();
        s  = rs[0] + rs[1] + rs[2] + rs[3];
        s2 = rs2[0] + rs2[1] + rs2[2] + rs2[3];
        float mu  = s * (1.f / DIMM);
        float var = s2 * (1.f / DIMM) - mu * mu;
        float rr  = rsqrtf(var + 1e-5f);
#pragma unroll
        for (int i = 0; i < 4; i++) {
            int c = tid + i * 256;
            float y = (v[i] - mu) * rr * bf2f(g[c]) + bf2f(bta[c]);
            out[(size_t)row * DIMM + c] = f2bf(y);
        }
    }
}

// ---------------- GEMM (single-buffer async staging, R4 structure) ----------------
// MODE 0: store bf16 C       MODE 1: Cres(fp32) atomic += acc(+bias@z0)  [fallback]
// MODE 2: bf16 gelu(acc+bias) MODE 3: slab[z] = acc (fp32, pure stores)
template <int MODE, int SPLITK>
__global__ __launch_bounds__(256) void gemm_bt(const unsigned short* __restrict__ A,
                                               const unsigned short* __restrict__ Bt,
                                               const unsigned short* __restrict__ bias,
                                               unsigned short* __restrict__ Cbf,
                                               float* __restrict__ Cres,
                                               int M, int N, int K) {
    __shared__ __align__(16) unsigned short As[128 * 32];
    __shared__ __align__(16) unsigned short Bs[128 * 32];
    const int tid = threadIdx.x;
    const int mBase = blockIdx.y * 128, nBase = blockIdx.x * 128;
    const int w = tid >> 6, lane = tid & 63;
    const int wm = (w >> 1) * 64, wn = (w & 1) * 64;
    const int quad = lane >> 4, l16 = lane & 15;
    const int kLen = K / SPLITK;
    const int kStart = (SPLITK > 1) ? blockIdx.z * kLen : 0;

    f32x4 acc[4][4];
#pragma unroll
    for (int i = 0; i < 4; i++)
#pragma unroll
        for (int j = 0; j < 4; j++) acc[i][j] = (f32x4){0.f, 0.f, 0.f, 0.f};

    // staging: wave w stages rows [w*32, w*32+32) of both tiles as 2 chunks of 16 rows; 16B/lane.
    const int lr = lane >> 2, lc = (lane & 3) * 8;
    const unsigned short* Ag = A  + (size_t)(mBase + w * 32 + lr) * K + kStart + lc;
    const unsigned short* Bg = Bt + (size_t)(nBase + w * 32 + lr) * K + kStart + lc;
    unsigned short* Al0 = &As[(w * 32) * 32];
    unsigned short* Al1 = &As[(w * 32 + 16) * 32];
    unsigned short* Bl0 = &Bs[(w * 32) * 32];
    unsigned short* Bl1 = &Bs[(w * 32 + 16) * 32];
    const size_t rstep = (size_t)16 * K;

    for (int k0 = 0; k0 < kLen; k0 += 32) {
        __syncthreads();
        gl_lds16(Ag + k0,         Al0);
        gl_lds16(Ag + k0 + rstep, Al1);
        gl_lds16(Bg + k0,         Bl0);
        gl_lds16(Bg + k0 + rstep, Bl1);
        __syncthreads();  // drains vmcnt before LDS reads

        bf16x8 af[4], bfv[4];
#pragma unroll
        for (int i = 0; i < 4; i++)
            af[i] = *(const bf16x8*)&As[(wm + i * 16 + l16) * 32 + quad * 8];
#pragma unroll
        for (int j = 0; j < 4; j++)
            bfv[j] = *(const bf16x8*)&Bs[(wn + j * 16 + l16) * 32 + quad * 8];
#pragma unroll
        for (int i = 0; i < 4; i++)
#pragma unroll
            for (int j = 0; j < 4; j++)
                acc[i][j] = __builtin_amdgcn_mfma_f32_16x16x32_bf16(af[i], bfv[j], acc[i][j], 0, 0, 0);
    }

    const size_t slabOff = (MODE == 3) ? (size_t)blockIdx.z * M * N : 0;
#pragma unroll
    for (int i = 0; i < 4; i++) {
#pragma unroll
        for (int j = 0; j < 4; j++) {
#pragma unroll
            for (int r = 0; r < 4; r++) {
                int m = mBase + wm + i * 16 + quad * 4 + r;
                int n = nBase + wn + j * 16 + l16;
                float v = acc[i][j][r];
                size_t idx = (size_t)m * N + n;
                if (MODE == 0) {
                    Cbf[idx] = f2bf(v);
                } else if (MODE == 1) {
                    if (SPLITK > 1) {
                        if (blockIdx.z == 0) v += bf2f(bias[n]);
                        atomicAdd(&Cres[idx], v);
                    } else {
                        Cres[idx] += v + bf2f(bias[n]);
                    }
                } else if (MODE == 2) {
                    float t2 = v + bf2f(bias[n]);
                    float gg = 0.5f * t2 * (1.f + erff(t2 * 0.70710678118f));
                    Cbf[idx] = f2bf(gg);
                } else {
                    Cres[slabOff + idx] = v;
                }
            }
        }
    }
}

// ---------------- MFMA flash attention ----------------
__global__ __launch_bounds__(256) void attn_mfma(const unsigned short* __restrict__ qkv,
                                                 const unsigned short* __restrict__ vt,
                                                 const unsigned long long* __restrict__ mbits,
                                                 unsigned short* __restrict__ o) {
    __shared__ __align__(16) unsigned short Ks[64 * 72];
    __shared__ __align__(16) unsigned short Vs[64 * 72];
    __shared__ __align__(16) unsigned short Ps[4][16 * 68];

    const int tid = threadIdx.x, w = tid >> 6, lane = tid & 63;
    const int quad = lane >> 4, l16 = lane & 15;
    const int qt = blockIdx.x, h = blockIdx.y, b = blockIdx.z;

    const size_t qrow = (size_t)(b * NSEQ + qt * 64 + w * 16 + l16) * 3072 + h * 64;
    bf16x8 qf[2];
    qf[0] = *(const bf16x8*)(qkv + qrow + quad * 8);
    qf[1] = *(const bf16x8*)(qkv + qrow + 32 + quad * 8);

    const int srow = tid >> 2, scol = (tid & 3) * 16;
    const unsigned short* kg_base = qkv + (size_t)(b * NSEQ) * 3072 + 1024 + h * 64;
    const unsigned short* vg_base = vt + (size_t)((b * HEADSN + h) * 64 + srow) * 1024;

    f32x4 oacc[4];
#pragma unroll
    for (int j = 0; j < 4; j++) oacc[j] = (f32x4){0.f, 0.f, 0.f, 0.f};
    float m_run[4], l_run[4];
#pragma unroll
    for (int r = 0; r < 4; r++) { m_run[r] = -1e30f; l_run[r] = 0.f; }

    const unsigned long long* mb =
        mbits + ((size_t)(b * NSEQ + qt * 64 + w * 16 + quad * 4)) * 16;

    for (int kt = 0; kt < 16; kt++) {
        __syncthreads();
        {
            const unsigned short* kg = kg_base + (size_t)(kt * 64 + srow) * 3072 + scol;
            uint4 k0 = *(const uint4*)kg;
            uint4 k1 = *(const uint4*)(kg + 8);
            const unsigned short* vg = vg_base + kt * 64 + scol;
            uint4 v0 = *(const uint4*)vg;
            uint4 v1 = *(const uint4*)(vg + 8);
            *(uint4*)&Ks[srow * 72 + scol]     = k0;
            *(uint4*)&Ks[srow * 72 + scol + 8] = k1;
            *(uint4*)&Vs[srow * 72 + scol]     = v0;
            *(uint4*)&Vs[srow * 72 + scol + 8] = v1;
        }
        __syncthreads();

        f32x4 sacc[4];
#pragma unroll
        for (int j = 0; j < 4; j++) sacc[j] = (f32x4){0.f, 0.f, 0.f, 0.f};
#pragma unroll
        for (int ks = 0; ks < 2; ks++) {
#pragma unroll
            for (int j = 0; j < 4; j++) {
                bf16x8 kf = *(const bf16x8*)&Ks[(j * 16 + l16) * 72 + ks * 32 + quad * 8];
                sacc[j] = __builtin_amdgcn_mfma_f32_16x16x32_bf16(qf[ks], kf, sacc[j], 0, 0, 0);
            }
        }

        unsigned long long mw[4];
#pragma unroll
        for (int r = 0; r < 4; r++) mw[r] = mb[r * 16 + kt];

        float sv[4][4];
        float tmax[4];
#pragma unroll
        for (int r = 0; r < 4; r++) {
            float mx = -1e30f;
#pragma unroll
            for (int j = 0; j < 4; j++) {
                float t = sacc[j][r] * 0.125f;
                int keep = (int)((mw[r] >> (j * 16 + l16)) & 1ull);
                t = keep ? t : -1e9f;
                sv[j][r] = t;
                mx = fmaxf(mx, t);
            }
#pragma unroll
            for (int off = 1; off < 16; off <<= 1)
                mx = fmaxf(mx, __shfl_xor(mx, off, 64));
            tmax[r] = mx;
        }
#pragma unroll
        for (int r = 0; r < 4; r++) {
            float m_new = fmaxf(m_run[r], tmax[r]);
            float alpha = __expf(m_run[r] - m_new);
            m_run[r] = m_new;
            float pj[4], ps = 0.f;
#pragma unroll
            for (int j = 0; j < 4; j++) {
                pj[j] = __expf(sv[j][r] - m_new);
                ps += pj[j];
            }
#pragma unroll
            for (int off = 1; off < 16; off <<= 1)
                ps += __shfl_xor(ps, off, 64);
            l_run[r] = l_run[r] * alpha + ps;
#pragma unroll
            for (int j = 0; j < 4; j++) {
                oacc[j][r] *= alpha;
                Ps[w][(quad * 4 + r) * 68 + j * 16 + l16] = f2bf(pj[j]);
            }
        }

#pragma unroll
        for (int ks = 0; ks < 2; ks++) {
            const unsigned short* pr = &Ps[w][l16 * 68 + ks * 32 + quad * 8];
            union { ushort4 u[2]; bf16x8 v; } af;
            af.u[0] = *(const ushort4*)pr;
            af.u[1] = *(const ushort4*)(pr + 4);
#pragma unroll
            for (int j = 0; j < 4; j++) {
                bf16x8 vf = *(const bf16x8*)&Vs[(j * 16 + l16) * 72 + ks * 32 + quad * 8];
                oacc[j] = __builtin_amdgcn_mfma_f32_16x16x32_bf16(af.v, vf, oacc[j], 0, 0, 0);
            }
        }
    }

#pragma unroll
    for (int j = 0; j < 4; j++) {
#pragma unroll
        for (int r = 0; r < 4; r++) {
            size_t row = (size_t)(b * NSEQ + qt * 64 + w * 16 + quad * 4 + r);
            o[row * 1024 + h * 64 + j * 16 + l16] = f2bf(oacc[j][r] / l_run[r]);
        }
    }
}

extern "C" void kernel_launch(void* const* d_in, const int* in_sizes, int n_in,
                              void* d_out, int out_size, void* d_ws, size_t ws_size,
                              hipStream_t stream) {
    const void* x     = d_in[0];
    const int*  mask  = (const int*)d_in[1];
    const void* ln1_g = d_in[2];
    const void* ln1_b = d_in[3];
    const void* qkv_w = d_in[4];
    const void* out_w = d_in[5];
    const void* out_b = d_in[6];
    const void* ln2_g = d_in[7];
    const void* ln2_b = d_in[8];
    const void* ff1_w = d_in[9];
    const void* ff1_b = d_in[10];
    const void* ff2_w = d_in[11];
    const void* ff2_b = d_in[12];

    char* ws = (char*)d_ws;
    float*          xf     = (float*)ws;                            // 8 MB fp32 residual
    unsigned short* h_bf   = (unsigned short*)(ws + (8u  << 20));   // 4 MB LN out
    unsigned short* qkv_bf = (unsigned short*)(ws + (12u << 20));   // 12 MB (attn half)
    unsigned short* ff_bf  = (unsigned short*)(ws + (12u << 20));   // 16 MB (ff half, reuses qkv+vt)
    unsigned short* vt_bf  = (unsigned short*)(ws + (24u << 20));   // 4 MB V^T (attn half)
    unsigned short* o_bf   = (unsigned short*)(ws + (28u << 20));   // 4 MB
    unsigned short* wT     = (unsigned short*)(ws + (32u << 20));   // 8 MB transposed weight
    unsigned short* vecs   = (unsigned short*)(ws + (40u << 20));   // 80 KB canonical vecs
    int*            flag   = (int*)(ws + (40u << 20) + (128u << 10));
    unsigned long long* mbits = (unsigned long long*)(ws + (40u << 20) + (192u << 10)); // 256 KB
    float*          slab   = (float*)(ws + (41u << 20));            // up to 32 MB split-K slabs

    const bool slabs_ok = ws_size >= (74ull << 20);

    sniff_kernel<<<1, 256, 0, stream>>>((const unsigned short*)x, flag);

    conv_all<<<dim3(64, 7), 256, 0, stream>>>(ln1_g, ln1_b, out_b, ln2_g, ln2_b, ff2_b, ff1_b,
                                              vecs, flag);
    mask_pack<<<512, 256, 0, stream>>>(mask, mbits);

    const int nx = MROWS * DIMM;  // 2M
    cvt_x<<<nx / 256, 256, 0, stream>>>(x, xf, flag);

    for (int l = 0; l < DEPTHN; l++) {
        const unsigned short* lv = vecs + l * VSTR;
        const unsigned short* lvn = vecs + (l + 1) * VSTR;  // next layer's vecs (l<3)

        // --- attention half ---
        if (l == 0)  // layers 1..3 get ln1 fused into the previous FF2 reduce
            ln_kernel<<<MROWS, 256, 0, stream>>>(xf, lv + 0, lv + 1024, h_bf);
        transpose_conv<<<dim3(3072 / 32, 1024 / 32), dim3(32, 8), 0, stream>>>(
            qkv_w, (size_t)l * 1024 * 3072, wT, 1024, 3072, flag);
        gemm_bt<0, 1><<<dim3(3072 / 128, MROWS / 128), 256, 0, stream>>>(
            h_bf, wT, nullptr, qkv_bf, nullptr, MROWS, 3072, 1024);
        vt_kernel<<<dim3(32, 32, BB), dim3(32, 8), 0, stream>>>(qkv_bf, vt_bf);
        attn_mfma<<<dim3(NSEQ / 64, HEADSN, BB), 256, 0, stream>>>(qkv_bf, vt_bf, mbits, o_bf);
        transpose_conv<<<dim3(1024 / 32, 1024 / 32), dim3(32, 8), 0, stream>>>(
            out_w, (size_t)l * 1024 * 1024, wT, 1024, 1024, flag);
        if (slabs_ok) {
            gemm_bt<3, 2><<<dim3(1024 / 128, MROWS / 128, 2), 256, 0, stream>>>(
                o_bf, wT, nullptr, nullptr, slab, MROWS, 1024, 1024);
            reduce_ln<2, 1><<<MROWS, 256, 0, stream>>>(
                slab, lv + 2048, xf, lv + 3072, lv + 4096, h_bf);
        } else {
            gemm_bt<1, 2><<<dim3(1024 / 128, MROWS / 128, 2), 256, 0, stream>>>(
                o_bf, wT, lv + 2048, nullptr, xf, MROWS, 1024, 1024);
            ln_kernel<<<MROWS, 256, 0, stream>>>(xf, lv + 3072, lv + 4096, h_bf);
        }

        // --- feedforward half ---
        transpose_conv<<<dim3(4096 / 32, 1024 / 32), dim3(32, 8), 0, stream>>>(
            ff1_w, (size_t)l * 1024 * 4096, wT, 1024, 4096, flag);
        gemm_bt<2, 1><<<dim3(4096 / 128, MROWS / 128), 256, 0, stream>>>(
            h_bf, wT, lv + 6144, ff_bf, nullptr, MROWS, 4096, 1024);
        transpose_conv<<<dim3(1024 / 32, 4096 / 32), dim3(32, 8), 0, stream>>>(
            ff2_w, (size_t)l * 4096 * 1024, wT, 4096, 1024, flag);
        if (slabs_ok) {
            gemm_bt<3, 4><<<dim3(1024 / 128, MROWS / 128, 4), 256, 0, stream>>>(
                ff_bf, wT, nullptr, nullptr, slab, MROWS, 1024, 4096);
            if (l < DEPTHN - 1)
                reduce_ln<4, 1><<<MROWS, 256, 0, stream>>>(
                    slab, lv + 5120, xf, lvn + 0, lvn + 1024, h_bf);
            else
                reduce_ln<4, 0><<<MROWS, 256, 0, stream>>>(
                    slab, lv + 5120, xf, nullptr, nullptr, nullptr);
        } else {
            gemm_bt<1, 4><<<dim3(1024 / 128, MROWS / 128, 4), 256, 0, stream>>>(
                ff_bf, wT, lv + 5120, nullptr, xf, MROWS, 1024, 4096);
            if (l < DEPTHN - 1)
                ln_kernel<<<MROWS, 256, 0, stream>>>(xf, lvn + 0, lvn + 1024, h_bf);
        }
    }

    store_out<<<nx / 256, 256, 0, stream>>>(xf, d_out, flag);
}